// Round 5
// baseline (552.241 us; speedup 1.0000x reference)
//
#include <hip/hip_runtime.h>
#include <stdint.h>

typedef unsigned short u16;
typedef __bf16 v8bf __attribute__((ext_vector_type(8)));
typedef float v4f __attribute__((ext_vector_type(4)));
typedef __attribute__((address_space(3))) unsigned lds_t;
typedef const __attribute__((address_space(1))) unsigned g_t;

__device__ __forceinline__ u16 f2bf(float f) {
  union { float f; unsigned u; } v; v.f = f;
  unsigned r = v.u + 0x7FFFu + ((v.u >> 16) & 1u);   // RNE
  return (u16)(r >> 16);
}
__device__ __forceinline__ float bf2f(u16 h) {
  union { unsigned u; float f; } v; v.u = ((unsigned)h) << 16;
  return v.f;
}
__device__ __forceinline__ ushort4 f4bf(float4 f) {
  ushort4 o;
  o.x = f2bf(f.x); o.y = f2bf(f.y); o.z = f2bf(f.z); o.w = f2bf(f.w);
  return o;
}

// ---------------- fp32 -> bf16 convert ----------------
__global__ void k_cvt(const float* __restrict__ s, u16* __restrict__ d, long n) {
  long i = ((long)blockIdx.x * blockDim.x + threadIdx.x) * 4;
  long stride = (long)gridDim.x * blockDim.x * 4;
  for (; i < n; i += stride) {
    *(ushort4*)(d + i) = f4bf(*(const float4*)(s + i));
  }
}

// ---------------- fused convert + 3-level pool (key/value) ----------------
__global__ void k_cvtpool(const float* __restrict__ src, u16* __restrict__ dst) {
  int g = blockIdx.x & 255, b = blockIdx.x >> 8;
  int c = threadIdx.x * 4;
  const float* p = src + ((long)b * 2048 + g * 8) * 1024 + c;
  u16* df = dst + ((long)b * 2048 + g * 8) * 1024 + c;
  float4 x[8];
#pragma unroll
  for (int j = 0; j < 8; j++) {
    x[j] = *(const float4*)(p + (long)j * 1024);
    *(ushort4*)(df + (long)j * 1024) = f4bf(x[j]);
  }
  float4 s2[4], s4[2], s8;
#pragma unroll
  for (int j = 0; j < 4; j++) {
    s2[j].x = x[2 * j].x + x[2 * j + 1].x;
    s2[j].y = x[2 * j].y + x[2 * j + 1].y;
    s2[j].z = x[2 * j].z + x[2 * j + 1].z;
    s2[j].w = x[2 * j].w + x[2 * j + 1].w;
  }
#pragma unroll
  for (int j = 0; j < 2; j++) {
    s4[j].x = s2[2 * j].x + s2[2 * j + 1].x;
    s4[j].y = s2[2 * j].y + s2[2 * j + 1].y;
    s4[j].z = s2[2 * j].z + s2[2 * j + 1].z;
    s4[j].w = s2[2 * j].w + s2[2 * j + 1].w;
  }
  s8.x = s4[0].x + s4[1].x; s8.y = s4[0].y + s4[1].y;
  s8.z = s4[0].z + s4[1].z; s8.w = s4[0].w + s4[1].w;
  u16* d2 = dst + ((long)8192 + b * 1024 + g * 4) * 1024 + c;
#pragma unroll
  for (int j = 0; j < 4; j++) {
    float4 t = {s2[j].x * 0.5f, s2[j].y * 0.5f, s2[j].z * 0.5f, s2[j].w * 0.5f};
    *(ushort4*)(d2 + (long)j * 1024) = f4bf(t);
  }
  u16* d4 = dst + ((long)12288 + b * 512 + g * 2) * 1024 + c;
#pragma unroll
  for (int j = 0; j < 2; j++) {
    float4 t = {s4[j].x * 0.25f, s4[j].y * 0.25f, s4[j].z * 0.25f, s4[j].w * 0.25f};
    *(ushort4*)(d4 + (long)j * 1024) = f4bf(t);
  }
  float4 t8 = {s8.x * 0.125f, s8.y * 0.125f, s8.z * 0.125f, s8.w * 0.125f};
  *(ushort4*)(dst + ((long)14336 + b * 256 + g) * 1024 + c) = f4bf(t8);
}

// ---------------- fp32 -> bf16 transpose-convert (32x32 tiles, batched z) ----
__global__ void k_tc(const float* __restrict__ src, u16* __restrict__ dst, int R, int C) {
  __shared__ float t[32][33];
  long zoff = (long)blockIdx.z * R * C;
  int r0 = blockIdx.y * 32, c0 = blockIdx.x * 32;
  int tx = threadIdx.x & 31, ty = threadIdx.x >> 5;
#pragma unroll
  for (int j = 0; j < 32; j += 8)
    t[ty + j][tx] = src[zoff + (long)(r0 + ty + j) * C + c0 + tx];
  __syncthreads();
#pragma unroll
  for (int j = 0; j < 32; j += 8)
    dst[zoff + (long)(c0 + ty + j) * R + r0 + tx] = f2bf(t[tx][ty + j]);
}

// ---------------- bias combines (fp32) ----------------
__global__ void k_bcomb_qkv(const float* __restrict__ in_w, const float* __restrict__ in_b,
                            const float* __restrict__ bq, const float* __restrict__ bk,
                            const float* __restrict__ bv, float* __restrict__ out) {
  int gw = (blockIdx.x * 256 + threadIdx.x) >> 6;   // 0..3071
  int lane = threadIdx.x & 63;
  int p = gw >> 10, j = gw & 1023, i = j >> 8, of = j & 255;
  const float* bp = p == 0 ? bq : p == 1 ? bk : bv;
  const float* row = in_w + ((long)i * 768 + p * 256 + of) * 256;
  float s = 0.f;
#pragma unroll
  for (int m = 0; m < 4; m++) s += row[lane + m * 64] * bp[i * 256 + lane + m * 64];
#pragma unroll
  for (int m = 32; m >= 1; m >>= 1) s += __shfl_xor(s, m, 64);
  if (lane == 0) out[gw] = in_b[(long)i * 768 + p * 256 + of] + s;
}

__global__ void k_bcomb_f(const float* __restrict__ fw, const float* __restrict__ fb,
                          const float* __restrict__ ob, float* __restrict__ out) {
  int w = (blockIdx.x * 256 + threadIdx.x) >> 6;    // 0..1023
  int lane = threadIdx.x & 63;
  const float* row = fw + (long)w * 1024;
  float s = 0.f;
  for (int k = lane; k < 1024; k += 64) s += row[k] * ob[k];
#pragma unroll
  for (int m = 32; m >= 1; m >>= 1) s += __shfl_xor(s, m, 64);
  if (lane == 0) out[w] = fb[w] + s;
}

// ---------------- scale-0 pass 1: per-row max m and denom l ----------------
// grid (1, 32, 8): y = 64-row q-tile, z = b*2+h.  Outputs M0/L0 [z][2048].
__global__ __launch_bounds__(256) void k_ml0(
    const u16* __restrict__ QHf, const u16* __restrict__ KH,
    float* __restrict__ M0, float* __restrict__ L0)
{
  int z = blockIdx.z;
  int b = z >> 1, h = z & 1;
  int q0 = blockIdx.y * 64;
  __shared__ u16 KV[2][128][32];
  __shared__ float red[2][4][64];

  const int tid = threadIdx.x, lane = tid & 63, wave = tid >> 6;
  const int q4 = lane >> 4, l16 = lane & 15;
  const int wr = (wave >> 1) * 32, wc = (wave & 1) * 64;
  const int srow = wave * 16 + (lane >> 2), scol = (lane & 3) * 8;
  const float alpha = 0.08838834764831845f;

  // Q fragments direct from global (one-time)
  v8bf qf[2][4];
#pragma unroll
  for (int mi = 0; mi < 2; mi++)
#pragma unroll
    for (int sub = 0; sub < 4; sub++)
      qf[mi][sub] = *(const v8bf*)(QHf + ((long)b * 2048 + q0 + wr + mi * 16 + l16) * 1024
                                   + h * 128 + sub * 32 + q4 * 8);

  const u16* gK = KH + (long)b * 2048 * 256 + h * 128;
  auto stageK = [&](int buf, int kt, int sub) {
    const u16* g = gK + (long)(kt * 128 + srow) * 256 + sub * 32 + scol;
    __builtin_amdgcn_global_load_lds((g_t*)g, (lds_t*)&KV[buf][wave * 16][0], 16, 0, 0);
    __builtin_amdgcn_global_load_lds((g_t*)(g + 64 * 256), (lds_t*)&KV[buf][64 + wave * 16][0], 16, 0, 0);
  };

  float m_run[2][4], l_run[2][4];
#pragma unroll
  for (int mi = 0; mi < 2; mi++)
#pragma unroll
    for (int i4 = 0; i4 < 4; i4++) { m_run[mi][i4] = -1e30f; l_run[mi][i4] = 0.f; }

  for (int kt = 0; kt < 16; kt++) {
    v4f s[2][4];
#pragma unroll
    for (int mi = 0; mi < 2; mi++)
#pragma unroll
      for (int ni = 0; ni < 4; ni++) s[mi][ni] = (v4f){0.f, 0.f, 0.f, 0.f};
    stageK(0, kt, 0);
    __syncthreads();
    int cur = 0;
#pragma unroll
    for (int sub = 0; sub < 4; sub++) {
      if (sub < 3) stageK(cur ^ 1, kt, sub + 1);
      v8bf kf[4];
#pragma unroll
      for (int ni = 0; ni < 4; ni++)
        kf[ni] = *(const v8bf*)&KV[cur][wc + ni * 16 + l16][q4 * 8];
#pragma unroll
      for (int mi = 0; mi < 2; mi++)
#pragma unroll
        for (int ni = 0; ni < 4; ni++)
          s[mi][ni] = __builtin_amdgcn_mfma_f32_16x16x32_bf16(qf[mi][sub], kf[ni], s[mi][ni], 0, 0, 0);
      __syncthreads();
      cur ^= 1;
    }
#pragma unroll
    for (int mi = 0; mi < 2; mi++)
#pragma unroll
      for (int ni = 0; ni < 4; ni++) s[mi][ni] *= alpha;
    float mloc[2][4];
#pragma unroll
    for (int mi = 0; mi < 2; mi++)
#pragma unroll
      for (int i4 = 0; i4 < 4; i4++)
        mloc[mi][i4] = fmaxf(fmaxf(s[mi][0][i4], s[mi][1][i4]),
                             fmaxf(s[mi][2][i4], s[mi][3][i4]));
#pragma unroll
    for (int d = 1; d <= 8; d <<= 1)
#pragma unroll
      for (int mi = 0; mi < 2; mi++)
#pragma unroll
        for (int i4 = 0; i4 < 4; i4++)
          mloc[mi][i4] = fmaxf(mloc[mi][i4], __shfl_xor(mloc[mi][i4], d, 64));
    if (l16 == 0) {
#pragma unroll
      for (int mi = 0; mi < 2; mi++)
#pragma unroll
        for (int i4 = 0; i4 < 4; i4++)
          red[0][wave][wr + mi * 16 + q4 * 4 + i4] = mloc[mi][i4];
    }
    __syncthreads();
    float lloc[2][4] = {{0.f, 0.f, 0.f, 0.f}, {0.f, 0.f, 0.f, 0.f}};
#pragma unroll
    for (int mi = 0; mi < 2; mi++)
#pragma unroll
      for (int i4 = 0; i4 < 4; i4++) {
        int rr = wr + mi * 16 + q4 * 4 + i4;
        float mn = fmaxf(fmaxf(red[0][wave][rr], red[0][wave ^ 1][rr]), m_run[mi][i4]);
        float scl = __expf(m_run[mi][i4] - mn);
        m_run[mi][i4] = mn;
        l_run[mi][i4] *= scl;
#pragma unroll
        for (int ni = 0; ni < 4; ni++)
          lloc[mi][i4] += __expf(s[mi][ni][i4] - mn);
      }
#pragma unroll
    for (int d = 1; d <= 8; d <<= 1)
#pragma unroll
      for (int mi = 0; mi < 2; mi++)
#pragma unroll
        for (int i4 = 0; i4 < 4; i4++)
          lloc[mi][i4] += __shfl_xor(lloc[mi][i4], d, 64);
    if (l16 == 0) {
#pragma unroll
      for (int mi = 0; mi < 2; mi++)
#pragma unroll
        for (int i4 = 0; i4 < 4; i4++)
          red[1][wave][wr + mi * 16 + q4 * 4 + i4] = lloc[mi][i4];
    }
    __syncthreads();
#pragma unroll
    for (int mi = 0; mi < 2; mi++)
#pragma unroll
      for (int i4 = 0; i4 < 4; i4++) {
        int rr = wr + mi * 16 + q4 * 4 + i4;
        l_run[mi][i4] += red[1][wave][rr] + red[1][wave ^ 1][rr];
      }
    __syncthreads();
  }

  if ((wave & 1) == 0 && l16 == 0) {
#pragma unroll
    for (int mi = 0; mi < 2; mi++)
#pragma unroll
      for (int i4 = 0; i4 < 4; i4++) {
        int r = q0 + wr + mi * 16 + q4 * 4 + i4;
        M0[(long)z * 2048 + r] = m_run[mi][i4];
        L0[(long)z * 2048 + r] = l_run[mi][i4];
      }
  }
}

// ---------------- scale-0 pass 2: P (both heads), W0, O = P.V ----------------
// grid (1, 64, 4): y = 32-row q-tile, z = b.  m,l precomputed -> no reductions.
__global__ __launch_bounds__(256) void k_pv0(
    const u16* __restrict__ QHf, const u16* __restrict__ KH,
    const u16* __restrict__ VHT, const float* __restrict__ M0,
    const float* __restrict__ L0, u16* __restrict__ AOf, float* __restrict__ W0)
{
  int b = blockIdx.z;
  int q0 = blockIdx.y * 32;
  __shared__ u16 P[2][32][136];
  __shared__ u16 KV[2][128][32];

  const int tid = threadIdx.x, lane = tid & 63, wave = tid >> 6;
  const int q4 = lane >> 4, l16 = lane & 15;
  const int wr = (wave >> 1) * 16, wc = (wave & 1) * 64;
  const int srow = wave * 16 + (lane >> 2), scol = (lane & 3) * 8;
  const float alpha = 0.08838834764831845f;

  // Q fragments (both heads) direct from global
  v8bf qf[2][4];
#pragma unroll
  for (int h = 0; h < 2; h++)
#pragma unroll
    for (int sub = 0; sub < 4; sub++)
      qf[h][sub] = *(const v8bf*)(QHf + ((long)b * 2048 + q0 + wr + l16) * 1024
                                  + h * 128 + sub * 32 + q4 * 8);
  // per-row softmax constants
  float mv[2][4], il[2][4];
#pragma unroll
  for (int h = 0; h < 2; h++)
#pragma unroll
    for (int i4 = 0; i4 < 4; i4++) {
      long r = (long)(b * 2 + h) * 2048 + q0 + wr + q4 * 4 + i4;
      mv[h][i4] = M0[r];
      il[h][i4] = 1.0f / L0[r];
    }

  const u16* gK = KH + (long)b * 2048 * 256;
  auto stageK = [&](int buf, int h, int kt, int sub) {
    const u16* g = gK + (long)(kt * 128 + srow) * 256 + h * 128 + sub * 32 + scol;
    __builtin_amdgcn_global_load_lds((g_t*)g, (lds_t*)&KV[buf][wave * 16][0], 16, 0, 0);
    __builtin_amdgcn_global_load_lds((g_t*)(g + 64 * 256), (lds_t*)&KV[buf][64 + wave * 16][0], 16, 0, 0);
  };
  auto stageV = [&](int buf, int h, int kt, int sub) {
    const u16* g = VHT + ((long)(b * 2 + h) * 128 + srow) * 2048 + kt * 128 + sub * 32 + scol;
    __builtin_amdgcn_global_load_lds((g_t*)g, (lds_t*)&KV[buf][wave * 16][0], 16, 0, 0);
    __builtin_amdgcn_global_load_lds((g_t*)(g + (long)64 * 2048), (lds_t*)&KV[buf][64 + wave * 16][0], 16, 0, 0);
  };

  v4f acc[2][4];
#pragma unroll
  for (int h = 0; h < 2; h++)
#pragma unroll
    for (int ni = 0; ni < 4; ni++) acc[h][ni] = (v4f){0.f, 0.f, 0.f, 0.f};

  for (int kt = 0; kt < 16; kt++) {
    float p0[4][4];
    // ---- QK + P for head 0 then head 1 ----
#pragma unroll
    for (int h = 0; h < 2; h++) {
      v4f s[4];
#pragma unroll
      for (int ni = 0; ni < 4; ni++) s[ni] = (v4f){0.f, 0.f, 0.f, 0.f};
      stageK(0, h, kt, 0);
      __syncthreads();
      int cur = 0;
#pragma unroll
      for (int sub = 0; sub < 4; sub++) {
        if (sub < 3) stageK(cur ^ 1, h, kt, sub + 1);
        v8bf kf[4];
#pragma unroll
        for (int ni = 0; ni < 4; ni++)
          kf[ni] = *(const v8bf*)&KV[cur][wc + ni * 16 + l16][q4 * 8];
#pragma unroll
        for (int ni = 0; ni < 4; ni++)
          s[ni] = __builtin_amdgcn_mfma_f32_16x16x32_bf16(qf[h][sub], kf[ni], s[ni], 0, 0, 0);
        __syncthreads();
        cur ^= 1;
      }
#pragma unroll
      for (int ni = 0; ni < 4; ni++)
#pragma unroll
        for (int i4 = 0; i4 < 4; i4++) {
          float p = __expf(s[ni][i4] * alpha - mv[h][i4]) * il[h][i4];
          P[h][wr + q4 * 4 + i4][wc + ni * 16 + l16] = f2bf(p);
          if (h == 0) p0[ni][i4] = p;
          else {
            W0[((long)b * 2048 + q0 + wr + q4 * 4 + i4) * 2048
               + kt * 128 + wc + ni * 16 + l16] = 0.5f * (p0[ni][i4] + p);
          }
        }
    }
    // ---- O += P.V for head 0 then head 1 ----
#pragma unroll
    for (int h = 0; h < 2; h++) {
      stageV(0, h, kt, 0);
      __syncthreads();                 // also makes P writes visible
      int cv = 0;
#pragma unroll
      for (int sub = 0; sub < 4; sub++) {
        if (sub < 3) stageV(cv ^ 1, h, kt, sub + 1);
        v8bf pf = *(const v8bf*)&P[h][wr + l16][sub * 32 + q4 * 8];
        v8bf vf[4];
#pragma unroll
        for (int ni = 0; ni < 4; ni++)
          vf[ni] = *(const v8bf*)&KV[cv][wc + ni * 16 + l16][q4 * 8];
#pragma unroll
        for (int ni = 0; ni < 4; ni++)
          acc[h][ni] = __builtin_amdgcn_mfma_f32_16x16x32_bf16(pf, vf[ni], acc[h][ni], 0, 0, 0);
        __syncthreads();
        cv ^= 1;
      }
    }
  }

  // ---- write AOf (already normalized) ----
#pragma unroll
  for (int h = 0; h < 2; h++)
#pragma unroll
    for (int ni = 0; ni < 4; ni++)
#pragma unroll
      for (int i4 = 0; i4 < 4; i4++) {
        int r = q0 + wr + q4 * 4 + i4;
        int c = wc + ni * 16 + l16;
        AOf[((long)b * 2048 + r) * 1024 + h * 128 + c] = f2bf(acc[h][ni][i4]);
      }
}

// ---------------- flash attention for scales 1..3 (unchanged) ----------------
__global__ __launch_bounds__(256) void k_flash(
    const u16* __restrict__ QHf, const u16* __restrict__ KH,
    const u16* __restrict__ VHT, u16* __restrict__ AOf)
{
  int z = blockIdx.z;
  int i = (z >> 3) + 1;
  int b = (z >> 1) & 3, h = z & 1;
  int Ls = 2048 >> i;
  int nkt = Ls >> 7;
  long ro = (long)(16384 - (8192 >> (i - 1))) * 256;
  int q0 = blockIdx.y * 64;

  __shared__ u16 QP[64][136];
  __shared__ u16 KV[2][128][32];
  __shared__ float red[2][4][64];

  const int tid = threadIdx.x, lane = tid & 63, wave = tid >> 6;
  const int q4 = lane >> 4, l16 = lane & 15;
  const int wr = (wave >> 1) * 32, wc = (wave & 1) * 64;
  const int srow = wave * 16 + (lane >> 2);
  const int scol = (lane & 3) * 8;

  {
    const u16* gq = QHf + ((long)b * 2048 + q0) * 1024 + i * 256 + h * 128;
    int idx = tid * 4;
#pragma unroll
    for (int j = 0; j < 4; j++) {
      int r = (idx + j) >> 4, ch = (idx + j) & 15;
      *(ulonglong2*)&QP[r][ch * 8] = *(const ulonglong2*)(gq + (long)r * 1024 + ch * 8);
    }
  }
  __syncthreads();
  v8bf qf[2][4];
#pragma unroll
  for (int mi = 0; mi < 2; mi++)
#pragma unroll
    for (int sub = 0; sub < 4; sub++)
      qf[mi][sub] = *(const v8bf*)&QP[wr + mi * 16 + l16][sub * 32 + q4 * 8];
  __syncthreads();

  const u16* gK = KH + ro + (long)b * Ls * 256 + h * 128;
  const u16* gV = VHT + ro + (long)(b * 2 + h) * 128 * Ls;

  auto stageK = [&](int buf, int kt, int sub) {
    const u16* g = gK + (long)(kt * 128 + srow) * 256 + sub * 32 + scol;
    __builtin_amdgcn_global_load_lds((g_t*)g, (lds_t*)&KV[buf][wave * 16][0], 16, 0, 0);
    __builtin_amdgcn_global_load_lds((g_t*)(g + 64 * 256), (lds_t*)&KV[buf][64 + wave * 16][0], 16, 0, 0);
  };
  auto stageV = [&](int buf, int kt, int sub) {
    const u16* g = gV + (long)srow * Ls + kt * 128 + sub * 32 + scol;
    __builtin_amdgcn_global_load_lds((g_t*)g, (lds_t*)&KV[buf][wave * 16][0], 16, 0, 0);
    __builtin_amdgcn_global_load_lds((g_t*)(g + (long)64 * Ls), (lds_t*)&KV[buf][64 + wave * 16][0], 16, 0, 0);
  };

  v4f acc_o[2][4];
  float m_run[2][4], l_run[2][4];
#pragma unroll
  for (int mi = 0; mi < 2; mi++)
#pragma unroll
    for (int ni = 0; ni < 4; ni++) acc_o[mi][ni] = (v4f){0.f, 0.f, 0.f, 0.f};
#pragma unroll
  for (int mi = 0; mi < 2; mi++)
#pragma unroll
    for (int i4 = 0; i4 < 4; i4++) { m_run[mi][i4] = -1e30f; l_run[mi][i4] = 0.f; }

  const float alpha = 0.08838834764831845f;

  for (int kt = 0; kt < nkt; kt++) {
    v4f s[2][4];
#pragma unroll
    for (int mi = 0; mi < 2; mi++)
#pragma unroll
      for (int ni = 0; ni < 4; ni++) s[mi][ni] = (v4f){0.f, 0.f, 0.f, 0.f};
    stageK(0, kt, 0);
    __syncthreads();
    int cur = 0;
#pragma unroll
    for (int sub = 0; sub < 4; sub++) {
      if (sub < 3) stageK(cur ^ 1, kt, sub + 1);
      v8bf kf[4];
#pragma unroll
      for (int ni = 0; ni < 4; ni++)
        kf[ni] = *(const v8bf*)&KV[cur][wc + ni * 16 + l16][q4 * 8];
#pragma unroll
      for (int mi = 0; mi < 2; mi++)
#pragma unroll
        for (int ni = 0; ni < 4; ni++)
          s[mi][ni] = __builtin_amdgcn_mfma_f32_16x16x32_bf16(qf[mi][sub], kf[ni], s[mi][ni], 0, 0, 0);
      __syncthreads();
      cur ^= 1;
    }
    stageV(0, kt, 0);

#pragma unroll
    for (int mi = 0; mi < 2; mi++)
#pragma unroll
      for (int ni = 0; ni < 4; ni++) s[mi][ni] *= alpha;
    float mloc[2][4];
#pragma unroll
    for (int mi = 0; mi < 2; mi++)
#pragma unroll
      for (int i4 = 0; i4 < 4; i4++)
        mloc[mi][i4] = fmaxf(fmaxf(s[mi][0][i4], s[mi][1][i4]),
                             fmaxf(s[mi][2][i4], s[mi][3][i4]));
#pragma unroll
    for (int d = 1; d <= 8; d <<= 1)
#pragma unroll
      for (int mi = 0; mi < 2; mi++)
#pragma unroll
        for (int i4 = 0; i4 < 4; i4++)
          mloc[mi][i4] = fmaxf(mloc[mi][i4], __shfl_xor(mloc[mi][i4], d, 64));
    if (l16 == 0) {
#pragma unroll
      for (int mi = 0; mi < 2; mi++)
#pragma unroll
        for (int i4 = 0; i4 < 4; i4++)
          red[0][wave][wr + mi * 16 + q4 * 4 + i4] = mloc[mi][i4];
    }
    __syncthreads();
    float scl[2][4];
#pragma unroll
    for (int mi = 0; mi < 2; mi++)
#pragma unroll
      for (int i4 = 0; i4 < 4; i4++) {
        int rr = wr + mi * 16 + q4 * 4 + i4;
        float mn = fmaxf(fmaxf(red[0][wave][rr], red[0][wave ^ 1][rr]), m_run[mi][i4]);
        scl[mi][i4] = __expf(m_run[mi][i4] - mn);
        m_run[mi][i4] = mn;
      }
    float lloc[2][4] = {{0.f, 0.f, 0.f, 0.f}, {0.f, 0.f, 0.f, 0.f}};
#pragma unroll
    for (int mi = 0; mi < 2; mi++)
#pragma unroll
      for (int ni = 0; ni < 4; ni++)
#pragma unroll
        for (int i4 = 0; i4 < 4; i4++) {
          float p = __expf(s[mi][ni][i4] - m_run[mi][i4]);
          lloc[mi][i4] += p;
          QP[wr + mi * 16 + q4 * 4 + i4][wc + ni * 16 + l16] = f2bf(p);
        }
#pragma unroll
    for (int d = 1; d <= 8; d <<= 1)
#pragma unroll
      for (int mi = 0; mi < 2; mi++)
#pragma unroll
        for (int i4 = 0; i4 < 4; i4++)
          lloc[mi][i4] += __shfl_xor(lloc[mi][i4], d, 64);
    if (l16 == 0) {
#pragma unroll
      for (int mi = 0; mi < 2; mi++)
#pragma unroll
        for (int i4 = 0; i4 < 4; i4++)
          red[1][wave][wr + mi * 16 + q4 * 4 + i4] = lloc[mi][i4];
    }
#pragma unroll
    for (int mi = 0; mi < 2; mi++)
#pragma unroll
      for (int ni = 0; ni < 4; ni++)
#pragma unroll
        for (int i4 = 0; i4 < 4; i4++) acc_o[mi][ni][i4] *= scl[mi][i4];
    __syncthreads();
#pragma unroll
    for (int mi = 0; mi < 2; mi++)
#pragma unroll
      for (int i4 = 0; i4 < 4; i4++) {
        int rr = wr + mi * 16 + q4 * 4 + i4;
        l_run[mi][i4] = l_run[mi][i4] * scl[mi][i4] + red[1][wave][rr] + red[1][wave ^ 1][rr];
      }

    int cv = 0;
#pragma unroll
    for (int sub = 0; sub < 4; sub++) {
      if (sub < 3) stageV(cv ^ 1, kt, sub + 1);
      v8bf pf[2], vf[4];
#pragma unroll
      for (int mi = 0; mi < 2; mi++)
        pf[mi] = *(const v8bf*)&QP[wr + mi * 16 + l16][sub * 32 + q4 * 8];
#pragma unroll
      for (int ni = 0; ni < 4; ni++)
        vf[ni] = *(const v8bf*)&KV[cv][wc + ni * 16 + l16][q4 * 8];
#pragma unroll
      for (int mi = 0; mi < 2; mi++)
#pragma unroll
        for (int ni = 0; ni < 4; ni++)
          acc_o[mi][ni] = __builtin_amdgcn_mfma_f32_16x16x32_bf16(pf[mi], vf[ni], acc_o[mi][ni], 0, 0, 0);
      __syncthreads();
      cv ^= 1;
    }
  }

#pragma unroll
  for (int mi = 0; mi < 2; mi++)
#pragma unroll
    for (int i4 = 0; i4 < 4; i4++) {
      float inv = 1.0f / l_run[mi][i4];
#pragma unroll
      for (int ni = 0; ni < 4; ni++) {
        int r = q0 + wr + mi * 16 + q4 * 4 + i4;
        int c = wc + ni * 16 + l16;
        AOf[((long)b * 2048 + r) * 1024 + i * 256 + h * 128 + c] =
            f2bf(acc_o[mi][ni][i4] * inv);
      }
    }
}

// ---------------- 128x128-tile batched bf16 MFMA GEMM (double-buffered) ----
template<int WBF>
__global__ __launch_bounds__(256) void k_gemm(
    const u16* __restrict__ A, long ldA, long sA1, long sA2,
    const u16* __restrict__ B, long ldB, long sB1, long sB2,
    void* __restrict__ Cv, long ldC, long sC1, long sC2, long sCk,
    const float* __restrict__ bias, long sBias, float alpha,
    int M, int N, int K, int nz2, int KS)
{
  __shared__ u16 As[2][128][32];
  __shared__ u16 Bs[2][128][32];
  int z = blockIdx.z;
  int ks = z % KS; int zz = z / KS;
  int z1 = zz / nz2, z2 = zz - z1 * nz2;
  A += (long)z1 * sA1 + (long)z2 * sA2 + (long)ks * K;
  B += (long)z1 * sB1 + (long)z2 * sB2 + (long)ks * K;
  long coff = (long)z1 * sC1 + (long)z2 * sC2 + (long)ks * sCk;
  const float* bz = bias ? bias + (long)z2 * sBias : nullptr;
  const int m0 = blockIdx.y * 128, n0 = blockIdx.x * 128;
  const int tid = threadIdx.x;
  const int lane = tid & 63;
  const int wave = tid >> 6;
  const int wr = (wave >> 1) * 64, wc = (wave & 1) * 64;
  const int q4 = lane >> 4, l16 = lane & 15;

  const int srow = wave * 16 + (lane >> 2);
  const int scol = (lane & 3) * 8;
  const u16* gA = A + (long)(m0 + srow) * ldA + scol;
  const u16* gB = B + (long)(n0 + srow) * ldB + scol;

  auto stage = [&](int buf, int kt) {
    __builtin_amdgcn_global_load_lds((g_t*)(gA + kt), (lds_t*)&As[buf][wave * 16][0], 16, 0, 0);
    __builtin_amdgcn_global_load_lds((g_t*)(gA + 64 * ldA + kt), (lds_t*)&As[buf][64 + wave * 16][0], 16, 0, 0);
    __builtin_amdgcn_global_load_lds((g_t*)(gB + kt), (lds_t*)&Bs[buf][wave * 16][0], 16, 0, 0);
    __builtin_amdgcn_global_load_lds((g_t*)(gB + 64 * ldB + kt), (lds_t*)&Bs[buf][64 + wave * 16][0], 16, 0, 0);
  };

  v4f acc[4][4];
#pragma unroll
  for (int i = 0; i < 4; i++)
#pragma unroll
    for (int j = 0; j < 4; j++) acc[i][j] = (v4f){0.f, 0.f, 0.f, 0.f};

  stage(0, 0);
  __syncthreads();
  int cur = 0;
  for (int kt = 0; kt < K; kt += 32) {
    if (kt + 32 < K) stage(cur ^ 1, kt + 32);
    v8bf af[4], bf[4];
#pragma unroll
    for (int i = 0; i < 4; i++) af[i] = *(const v8bf*)&As[cur][wr + i * 16 + l16][q4 * 8];
#pragma unroll
    for (int i = 0; i < 4; i++) bf[i] = *(const v8bf*)&Bs[cur][wc + i * 16 + l16][q4 * 8];
#pragma unroll
    for (int mi = 0; mi < 4; mi++)
#pragma unroll
      for (int ni = 0; ni < 4; ni++)
        acc[mi][ni] = __builtin_amdgcn_mfma_f32_16x16x32_bf16(af[mi], bf[ni], acc[mi][ni], 0, 0, 0);
    __syncthreads();
    cur ^= 1;
  }

#pragma unroll
  for (int mi = 0; mi < 4; mi++) {
    int rb = m0 + wr + mi * 16 + q4 * 4;
#pragma unroll
    for (int ni = 0; ni < 4; ni++) {
      int c = n0 + wc + ni * 16 + l16;
      float bv = bz ? bz[c] : 0.f;
#pragma unroll
      for (int i = 0; i < 4; i++) {
        int r = rb + i;
        float val = acc[mi][ni][i] * alpha + bv;
        if (WBF) ((u16*)Cv)[coff + (long)r * ldC + c] = f2bf(val);
        else     ((float*)Cv)[coff + (long)r * ldC + c] = val;
      }
    }
  }
}

// ---------------- K/V head GEMM, full 128x128 tiles, scale derived from row ----
// grid (2, 120, 2): x = col block (N=256), y = row block over 15360, z: 0=K, 1=V.
__global__ __launch_bounds__(256) void k_gemm_kv(
    const u16* __restrict__ Xk, const u16* __restrict__ Xv,
    const u16* __restrict__ WCkv, const float* __restrict__ Bckv,
    u16* __restrict__ KH, u16* __restrict__ VHT)
{
  __shared__ u16 As[2][128][32];
  __shared__ u16 Bs[2][128][32];
  const int isV = blockIdx.z;
  const int m0 = blockIdx.y * 128, n0 = blockIdx.x * 128;
  const int scale = m0 < 8192 ? 0 : (m0 < 12288 ? 1 : (m0 < 14336 ? 2 : 3));
  const int rbase = scale == 0 ? 0 : (scale == 1 ? 8192 : (scale == 2 ? 12288 : 14336));
  const int lsh = 11 - scale;
  const u16* A = isV ? Xv : Xk;
  const u16* B = WCkv + (long)isV * 1048576 + (long)scale * 262144;
  const float* bz = Bckv + isV * 1024 + scale * 256;

  const int tid = threadIdx.x;
  const int lane = tid & 63, wave = tid >> 6;
  const int wr = (wave >> 1) * 64, wc = (wave & 1) * 64;
  const int q4 = lane >> 4, l16 = lane & 15;
  const int srow = wave * 16 + (lane >> 2);
  const int scol = (lane & 3) * 8;
  const u16* gA = A + (long)(m0 + srow) * 1024 + scol;
  const u16* gB = B + (long)(n0 + srow) * 1024 + scol;

  auto stage = [&](int buf, int kt) {
    __builtin_amdgcn_global_load_lds((g_t*)(gA + kt), (lds_t*)&As[buf][wave * 16][0], 16, 0, 0);
    __builtin_amdgcn_global_load_lds((g_t*)(gA + 64 * 1024 + kt), (lds_t*)&As[buf][64 + wave * 16][0], 16, 0, 0);
    __builtin_amdgcn_global_load_lds((g_t*)(gB + kt), (lds_t*)&Bs[buf][wave * 16][0], 16, 0, 0);
    __builtin_amdgcn_global_load_lds((g_t*)(gB + 64 * 1024 + kt), (lds_t*)&Bs[buf][64 + wave * 16][0], 16, 0, 0);
  };

  v4f acc[4][4];
#pragma unroll
  for (int i = 0; i < 4; i++)
#pragma unroll
    for (int j = 0; j < 4; j++) acc[i][j] = (v4f){0.f, 0.f, 0.f, 0.f};

  stage(0, 0);
  __syncthreads();
  int cur = 0;
  for (int kt = 0; kt < 1024; kt += 32) {
    if (kt + 32 < 1024) stage(cur ^ 1, kt + 32);
    v8bf af[4], bf[4];
#pragma unroll
    for (int i = 0; i < 4; i++) af[i] = *(const v8bf*)&As[cur][wr + i * 16 + l16][q4 * 8];
#pragma unroll
    for (int i = 0; i < 4; i++) bf[i] = *(const v8bf*)&Bs[cur][wc + i * 16 + l16][q4 * 8];
#pragma unroll
    for (int mi = 0; mi < 4; mi++)
#pragma unroll
      for (int ni = 0; ni < 4; ni++)
        acc[mi][ni] = __builtin_amdgcn_mfma_f32_16x16x32_bf16(af[mi], bf[ni], acc[mi][ni], 0, 0, 0);
    __syncthreads();
    cur ^= 1;
  }

#pragma unroll
  for (int mi = 0; mi < 4; mi++) {
    int rb = m0 + wr + mi * 16 + q4 * 4;
#pragma unroll
    for (int ni = 0; ni < 4; ni++) {
      int c = n0 + wc + ni * 16 + l16;
      float bv = bz[c];
#pragma unroll
      for (int i = 0; i < 4; i++) {
        int r = rb + i;
        float val = acc[mi][ni][i] + bv;
        if (!isV) {
          KH[(long)r * 256 + c] = f2bf(val);
        } else {
          int rl = r - rbase;
          int b = rl >> lsh, t = rl & ((1 << lsh) - 1);
          int h = c >> 7, n = c & 127;
          VHT[(long)rbase * 256 + (((long)(b * 2 + h) * 128 + n) << lsh) + t] = f2bf(val);
        }
      }
    }
  }
}

extern "C" void kernel_launch(void* const* d_in, const int* in_sizes, int n_in,
                              void* d_out, int out_size, void* d_ws, size_t ws_size,
                              hipStream_t stream) {
  const float* query = (const float*)d_in[0];
  const float* key_  = (const float*)d_in[1];
  const float* value = (const float*)d_in[2];
  const float* wq    = (const float*)d_in[3];
  const float* bq    = (const float*)d_in[4];
  const float* wk    = (const float*)d_in[5];
  const float* bk    = (const float*)d_in[6];
  const float* wv    = (const float*)d_in[7];
  const float* bv    = (const float*)d_in[8];
  const float* in_w  = (const float*)d_in[9];
  const float* in_b  = (const float*)d_in[10];
  const float* out_w = (const float*)d_in[11];
  const float* out_b = (const float*)d_in[12];
  const float* fus_w = (const float*)d_in[13];
  const float* fus_b = (const float*)d_in[14];
  (void)in_sizes; (void)n_in; (void)out_size; (void)ws_size;

  float* outF  = (float*)d_out;
  float* outW0 = outF + (long)4 * 2048 * 1024;

  // ---- workspace layout ----
  char* base = (char*)d_ws;
  size_t off = 0;
  auto alloc = [&](size_t bytes) -> void* {
    void* p = base + off;
    off = (off + bytes + 255) & ~(size_t)255;
    return p;
  };
  const long NX = (long)8192 * 1024;
  u16* Winb = (u16*)alloc((size_t)4 * 768 * 256 * 2);     // bf16 in_w
  u16* Wfb  = (u16*)alloc((size_t)1024 * 1024 * 2);       // bf16 fus_w
  u16* WoT  = (u16*)alloc((size_t)4 * 256 * 256 * 2);     // bf16 out_w^T (per scale)
  u16* WT   = (u16*)alloc((size_t)3 * 1024 * 1024 * 2);   // bf16 wq^T|wk^T|wv^T
  u16* WC   = (u16*)alloc((size_t)3 * 1024 * 1024 * 2);   // combined WQc|WKc|WVc
  u16* WFc  = (u16*)alloc((size_t)1024 * 1024 * 2);       // combined final weight
  float* Bc  = (float*)alloc((size_t)3 * 1024 * 4);       // combined bQc|bKc|bVc
  float* fbc = (float*)alloc((size_t)1024 * 4);           // combined final bias
  u16* Xq    = (u16*)alloc((size_t)NX * 2);
  u16* XkAll = (u16*)alloc((size_t)15360 * 1024 * 2);
  u16* XvAll = (u16*)alloc((size_t)15360 * 1024 * 2);
  u16* QHf = (u16*)alloc((size_t)8192 * 1024 * 2);        // heads of Q, 1024-wide
  u16* KH  = (u16*)alloc((size_t)15360 * 256 * 2);
  u16* VHT = (u16*)alloc((size_t)15360 * 256 * 2);
  float* M0 = (float*)alloc((size_t)8 * 2048 * 4);        // scale-0 row max
  float* L0 = (float*)alloc((size_t)8 * 2048 * 4);        // scale-0 row denom
  u16* AOf = (u16*)alloc((size_t)8192 * 1024 * 2);        // attended concat, 1024-wide

  // ---- converts / transposes / pooling ----
  k_cvt<<<1024, 256, 0, stream>>>(query, Xq, NX);
  k_cvtpool<<<1024, 256, 0, stream>>>(key_,  XkAll);
  k_cvtpool<<<1024, 256, 0, stream>>>(value, XvAll);
  k_cvt<<<192, 256, 0, stream>>>(in_w, Winb, 4 * 768 * 256);
  k_cvt<<<256, 256, 0, stream>>>(fus_w, Wfb, 1024 * 1024);
  k_tc<<<dim3(32, 32, 1), 256, 0, stream>>>(wq, WT, 1024, 1024);
  k_tc<<<dim3(32, 32, 1), 256, 0, stream>>>(wk, WT + (long)1024 * 1024, 1024, 1024);
  k_tc<<<dim3(32, 32, 1), 256, 0, stream>>>(wv, WT + (long)2 * 1024 * 1024, 1024, 1024);
  k_tc<<<dim3(8, 8, 4), 256, 0, stream>>>(out_w, WoT, 256, 256);
  k_bcomb_qkv<<<768, 256, 0, stream>>>(in_w, in_b, bq, bk, bv, Bc);
  k_bcomb_f<<<256, 256, 0, stream>>>(fus_w, fus_b, out_b, fbc);

  // ---- weight combines ----
  k_gemm<1><<<dim3(8, 2, 12), 256, 0, stream>>>(
      Winb, 256, 65536, 196608,
      WT, 1024, 1048576, 256,
      WC, 1024, 1048576, 262144, 0,
      nullptr, 0, 1.f, 256, 1024, 256, 4, 1);
  k_gemm<1><<<dim3(2, 8, 4), 256, 0, stream>>>(
      Wfb, 1024, 0, 256,
      WoT, 256, 0, 65536,
      WFc, 1024, 0, 256, 0,
      nullptr, 0, 1.f, 1024, 256, 256, 4, 1);

  // ---- head projections ----
  k_gemm<1><<<dim3(8, 64, 1), 256, 0, stream>>>(
      Xq, 1024, 0, 0, WC, 1024, 0, 0,
      QHf, 1024, 0, 0, 0, Bc, 0, 1.f, 8192, 1024, 1024, 1, 1);
  k_gemm_kv<<<dim3(2, 120, 2), 256, 0, stream>>>(
      XkAll, XvAll, WC + (long)1024 * 1024, Bc + 1024, KH, VHT);

  // ---- scale 0: two-pass fused (m,l then P/W0/PV) ----
  k_ml0<<<dim3(1, 32, 8), 256, 0, stream>>>(QHf, KH, M0, L0);
  k_pv0<<<dim3(1, 64, 4), 256, 0, stream>>>(QHf, KH, VHT, M0, L0, AOf, outW0);

  // ---- scales 1..3: fused flash attention ----
  k_flash<<<dim3(1, 32, 24), 256, 0, stream>>>(QHf, KH, VHT, AOf);

  // ---- final (fused out-proj + fusion): fused = AOf @ WFc^T + fbc ----
  k_gemm<0><<<dim3(8, 64, 1), 256, 0, stream>>>(
      AOf, 1024, 0, 0, WFc, 1024, 0, 0,
      outF, 1024, 0, 0, 0, fbc, 0, 1.f, 8192, 1024, 1024, 1, 1);
}

// Round 6
// 518.831 us; speedup vs baseline: 1.0644x; 1.0644x over previous
//
#include <hip/hip_runtime.h>
#include <stdint.h>

typedef unsigned short u16;
typedef __bf16 v8bf __attribute__((ext_vector_type(8)));
typedef float v4f __attribute__((ext_vector_type(4)));
typedef __attribute__((address_space(3))) unsigned lds_t;
typedef const __attribute__((address_space(1))) unsigned g_t;

__device__ __forceinline__ u16 f2bf(float f) {
  union { float f; unsigned u; } v; v.f = f;
  unsigned r = v.u + 0x7FFFu + ((v.u >> 16) & 1u);   // RNE
  return (u16)(r >> 16);
}
__device__ __forceinline__ float bf2f(u16 h) {
  union { unsigned u; float f; } v; v.u = ((unsigned)h) << 16;
  return v.f;
}
__device__ __forceinline__ ushort4 f4bf(float4 f) {
  ushort4 o;
  o.x = f2bf(f.x); o.y = f2bf(f.y); o.z = f2bf(f.z); o.w = f2bf(f.w);
  return o;
}

// ---------------- fp32 -> bf16 convert ----------------
__global__ void k_cvt(const float* __restrict__ s, u16* __restrict__ d, long n) {
  long i = ((long)blockIdx.x * blockDim.x + threadIdx.x) * 4;
  long stride = (long)gridDim.x * blockDim.x * 4;
  for (; i < n; i += stride) {
    *(ushort4*)(d + i) = f4bf(*(const float4*)(s + i));
  }
}

// ---------------- fused convert + 3-level pool (key/value) ----------------
__global__ void k_cvtpool(const float* __restrict__ src, u16* __restrict__ dst) {
  int g = blockIdx.x & 255, b = blockIdx.x >> 8;
  int c = threadIdx.x * 4;
  const float* p = src + ((long)b * 2048 + g * 8) * 1024 + c;
  u16* df = dst + ((long)b * 2048 + g * 8) * 1024 + c;
  float4 x[8];
#pragma unroll
  for (int j = 0; j < 8; j++) {
    x[j] = *(const float4*)(p + (long)j * 1024);
    *(ushort4*)(df + (long)j * 1024) = f4bf(x[j]);
  }
  float4 s2[4], s4[2], s8;
#pragma unroll
  for (int j = 0; j < 4; j++) {
    s2[j].x = x[2 * j].x + x[2 * j + 1].x;
    s2[j].y = x[2 * j].y + x[2 * j + 1].y;
    s2[j].z = x[2 * j].z + x[2 * j + 1].z;
    s2[j].w = x[2 * j].w + x[2 * j + 1].w;
  }
#pragma unroll
  for (int j = 0; j < 2; j++) {
    s4[j].x = s2[2 * j].x + s2[2 * j + 1].x;
    s4[j].y = s2[2 * j].y + s2[2 * j + 1].y;
    s4[j].z = s2[2 * j].z + s2[2 * j + 1].z;
    s4[j].w = s2[2 * j].w + s2[2 * j + 1].w;
  }
  s8.x = s4[0].x + s4[1].x; s8.y = s4[0].y + s4[1].y;
  s8.z = s4[0].z + s4[1].z; s8.w = s4[0].w + s4[1].w;
  u16* d2 = dst + ((long)8192 + b * 1024 + g * 4) * 1024 + c;
#pragma unroll
  for (int j = 0; j < 4; j++) {
    float4 t = {s2[j].x * 0.5f, s2[j].y * 0.5f, s2[j].z * 0.5f, s2[j].w * 0.5f};
    *(ushort4*)(d2 + (long)j * 1024) = f4bf(t);
  }
  u16* d4 = dst + ((long)12288 + b * 512 + g * 2) * 1024 + c;
#pragma unroll
  for (int j = 0; j < 2; j++) {
    float4 t = {s4[j].x * 0.25f, s4[j].y * 0.25f, s4[j].z * 0.25f, s4[j].w * 0.25f};
    *(ushort4*)(d4 + (long)j * 1024) = f4bf(t);
  }
  float4 t8 = {s8.x * 0.125f, s8.y * 0.125f, s8.z * 0.125f, s8.w * 0.125f};
  *(ushort4*)(dst + ((long)14336 + b * 256 + g) * 1024 + c) = f4bf(t8);
}

// ---------------- fp32 -> bf16 transpose-convert (32x32 tiles, batched z) ----
__global__ void k_tc(const float* __restrict__ src, u16* __restrict__ dst, int R, int C) {
  __shared__ float t[32][33];
  long zoff = (long)blockIdx.z * R * C;
  int r0 = blockIdx.y * 32, c0 = blockIdx.x * 32;
  int tx = threadIdx.x & 31, ty = threadIdx.x >> 5;
#pragma unroll
  for (int j = 0; j < 32; j += 8)
    t[ty + j][tx] = src[zoff + (long)(r0 + ty + j) * C + c0 + tx];
  __syncthreads();
#pragma unroll
  for (int j = 0; j < 32; j += 8)
    dst[zoff + (long)(c0 + ty + j) * R + r0 + tx] = f2bf(t[tx][ty + j]);
}

// ---------------- bias combines (fp32) ----------------
__global__ void k_bcomb_qkv(const float* __restrict__ in_w, const float* __restrict__ in_b,
                            const float* __restrict__ bq, const float* __restrict__ bk,
                            const float* __restrict__ bv, float* __restrict__ out) {
  int gw = (blockIdx.x * 256 + threadIdx.x) >> 6;   // 0..3071
  int lane = threadIdx.x & 63;
  int p = gw >> 10, j = gw & 1023, i = j >> 8, of = j & 255;
  const float* bp = p == 0 ? bq : p == 1 ? bk : bv;
  const float* row = in_w + ((long)i * 768 + p * 256 + of) * 256;
  float s = 0.f;
#pragma unroll
  for (int m = 0; m < 4; m++) s += row[lane + m * 64] * bp[i * 256 + lane + m * 64];
#pragma unroll
  for (int m = 32; m >= 1; m >>= 1) s += __shfl_xor(s, m, 64);
  if (lane == 0) out[gw] = in_b[(long)i * 768 + p * 256 + of] + s;
}

__global__ void k_bcomb_f(const float* __restrict__ fw, const float* __restrict__ fb,
                          const float* __restrict__ ob, float* __restrict__ out) {
  int w = (blockIdx.x * 256 + threadIdx.x) >> 6;    // 0..1023
  int lane = threadIdx.x & 63;
  const float* row = fw + (long)w * 1024;
  float s = 0.f;
  for (int k = lane; k < 1024; k += 64) s += row[k] * ob[k];
#pragma unroll
  for (int m = 32; m >= 1; m >>= 1) s += __shfl_xor(s, m, 64);
  if (lane == 0) out[w] = fb[w] + s;
}

// ---------------- split-K reduce into 1024-wide AO ----------
template<int KS>
__global__ __launch_bounds__(256) void k_ksum(const float* __restrict__ P,
                                              u16* __restrict__ O, long n, int coloff) {
  long i = ((long)blockIdx.x * 256 + threadIdx.x) * 4;
  if (i >= n) return;
  float4 s = *(const float4*)(P + i);
#pragma unroll
  for (int ks = 1; ks < KS; ks++) {
    float4 t = *(const float4*)(P + (long)ks * n + i);
    s.x += t.x; s.y += t.y; s.z += t.z; s.w += t.w;
  }
  *(ushort4*)(O + (i >> 8) * 1024 + coloff + (int)(i & 255)) = f4bf(s);
}

// ---------------- scale-0 pass 1: partial per-row (m,l) over 4 K-tiles ------
// grid (4, 32, 8): x = K chunk, y = 64-row q-tile, z = b*2+h.
// Outputs Mp/Lp [kc][z][2048].
__global__ __launch_bounds__(256) void k_ml0(
    const u16* __restrict__ QHf, const u16* __restrict__ KH,
    float* __restrict__ Mp, float* __restrict__ Lp)
{
  int kc = blockIdx.x;
  int z = blockIdx.z;
  int b = z >> 1, h = z & 1;
  int q0 = blockIdx.y * 64;
  __shared__ u16 KV[2][128][32];
  __shared__ float red[2][4][64];

  const int tid = threadIdx.x, lane = tid & 63, wave = tid >> 6;
  const int q4 = lane >> 4, l16 = lane & 15;
  const int wr = (wave >> 1) * 32, wc = (wave & 1) * 64;
  const int srow = wave * 16 + (lane >> 2), scol = (lane & 3) * 8;
  const float alpha = 0.08838834764831845f;

  v8bf qf[2][4];
#pragma unroll
  for (int mi = 0; mi < 2; mi++)
#pragma unroll
    for (int sub = 0; sub < 4; sub++)
      qf[mi][sub] = *(const v8bf*)(QHf + ((long)b * 2048 + q0 + wr + mi * 16 + l16) * 1024
                                   + h * 128 + sub * 32 + q4 * 8);

  const u16* gK = KH + (long)b * 2048 * 256 + h * 128;
  auto stageK = [&](int buf, int kt, int sub) {
    const u16* g = gK + (long)(kt * 128 + srow) * 256 + sub * 32 + scol;
    __builtin_amdgcn_global_load_lds((g_t*)g, (lds_t*)&KV[buf][wave * 16][0], 16, 0, 0);
    __builtin_amdgcn_global_load_lds((g_t*)(g + 64 * 256), (lds_t*)&KV[buf][64 + wave * 16][0], 16, 0, 0);
  };

  float m_run[2][4], l_run[2][4];
#pragma unroll
  for (int mi = 0; mi < 2; mi++)
#pragma unroll
    for (int i4 = 0; i4 < 4; i4++) { m_run[mi][i4] = -1e30f; l_run[mi][i4] = 0.f; }

  for (int kt = kc * 4; kt < kc * 4 + 4; kt++) {
    v4f s[2][4];
#pragma unroll
    for (int mi = 0; mi < 2; mi++)
#pragma unroll
      for (int ni = 0; ni < 4; ni++) s[mi][ni] = (v4f){0.f, 0.f, 0.f, 0.f};
    stageK(0, kt, 0);
    __syncthreads();
    int cur = 0;
#pragma unroll
    for (int sub = 0; sub < 4; sub++) {
      if (sub < 3) stageK(cur ^ 1, kt, sub + 1);
      v8bf kf[4];
#pragma unroll
      for (int ni = 0; ni < 4; ni++)
        kf[ni] = *(const v8bf*)&KV[cur][wc + ni * 16 + l16][q4 * 8];
#pragma unroll
      for (int mi = 0; mi < 2; mi++)
#pragma unroll
        for (int ni = 0; ni < 4; ni++)
          s[mi][ni] = __builtin_amdgcn_mfma_f32_16x16x32_bf16(qf[mi][sub], kf[ni], s[mi][ni], 0, 0, 0);
      __syncthreads();
      cur ^= 1;
    }
#pragma unroll
    for (int mi = 0; mi < 2; mi++)
#pragma unroll
      for (int ni = 0; ni < 4; ni++) s[mi][ni] *= alpha;
    float mloc[2][4];
#pragma unroll
    for (int mi = 0; mi < 2; mi++)
#pragma unroll
      for (int i4 = 0; i4 < 4; i4++)
        mloc[mi][i4] = fmaxf(fmaxf(s[mi][0][i4], s[mi][1][i4]),
                             fmaxf(s[mi][2][i4], s[mi][3][i4]));
#pragma unroll
    for (int d = 1; d <= 8; d <<= 1)
#pragma unroll
      for (int mi = 0; mi < 2; mi++)
#pragma unroll
        for (int i4 = 0; i4 < 4; i4++)
          mloc[mi][i4] = fmaxf(mloc[mi][i4], __shfl_xor(mloc[mi][i4], d, 64));
    if (l16 == 0) {
#pragma unroll
      for (int mi = 0; mi < 2; mi++)
#pragma unroll
        for (int i4 = 0; i4 < 4; i4++)
          red[0][wave][wr + mi * 16 + q4 * 4 + i4] = mloc[mi][i4];
    }
    __syncthreads();
    float lloc[2][4] = {{0.f, 0.f, 0.f, 0.f}, {0.f, 0.f, 0.f, 0.f}};
#pragma unroll
    for (int mi = 0; mi < 2; mi++)
#pragma unroll
      for (int i4 = 0; i4 < 4; i4++) {
        int rr = wr + mi * 16 + q4 * 4 + i4;
        float mn = fmaxf(fmaxf(red[0][wave][rr], red[0][wave ^ 1][rr]), m_run[mi][i4]);
        float scl = __expf(m_run[mi][i4] - mn);
        m_run[mi][i4] = mn;
        l_run[mi][i4] *= scl;
#pragma unroll
        for (int ni = 0; ni < 4; ni++)
          lloc[mi][i4] += __expf(s[mi][ni][i4] - mn);
      }
#pragma unroll
    for (int d = 1; d <= 8; d <<= 1)
#pragma unroll
      for (int mi = 0; mi < 2; mi++)
#pragma unroll
        for (int i4 = 0; i4 < 4; i4++)
          lloc[mi][i4] += __shfl_xor(lloc[mi][i4], d, 64);
    if (l16 == 0) {
#pragma unroll
      for (int mi = 0; mi < 2; mi++)
#pragma unroll
        for (int i4 = 0; i4 < 4; i4++)
          red[1][wave][wr + mi * 16 + q4 * 4 + i4] = lloc[mi][i4];
    }
    __syncthreads();
#pragma unroll
    for (int mi = 0; mi < 2; mi++)
#pragma unroll
      for (int i4 = 0; i4 < 4; i4++) {
        int rr = wr + mi * 16 + q4 * 4 + i4;
        l_run[mi][i4] += red[1][wave][rr] + red[1][wave ^ 1][rr];
      }
    __syncthreads();
  }

  if ((wave & 1) == 0 && l16 == 0) {
    long zo = ((long)kc * 8 + z) * 2048;
#pragma unroll
    for (int mi = 0; mi < 2; mi++)
#pragma unroll
      for (int i4 = 0; i4 < 4; i4++) {
        int r = q0 + wr + mi * 16 + q4 * 4 + i4;
        Mp[zo + r] = m_run[mi][i4];
        Lp[zo + r] = l_run[mi][i4];
      }
  }
}

// ---------------- combine partial (m,l): 4 chunks -> M0/L0 ----------------
__global__ __launch_bounds__(256) void k_mlcomb(
    const float* __restrict__ Mp, const float* __restrict__ Lp,
    float* __restrict__ M0, float* __restrict__ L0)
{
  long r = (long)blockIdx.x * 256 + threadIdx.x;    // 0..16383
  float m = -1e30f;
#pragma unroll
  for (int kc = 0; kc < 4; kc++) m = fmaxf(m, Mp[kc * 16384 + r]);
  float l = 0.f;
#pragma unroll
  for (int kc = 0; kc < 4; kc++)
    l += Lp[kc * 16384 + r] * __expf(Mp[kc * 16384 + r] - m);
  M0[r] = m; L0[r] = l;
}

// ---------------- scale-0 pass 2: P (both heads), W0, split-K O partials ----
// grid (4, 64, 4): x = K chunk (4 tiles = 512 cols), y = 32-row q-tile, z = b.
// m,l precomputed -> no reductions.  PP[kc][b*2048+r][h*128+c] fp32 partials.
__global__ __launch_bounds__(256) void k_pv0(
    const u16* __restrict__ QHf, const u16* __restrict__ KH,
    const u16* __restrict__ VHT, const float* __restrict__ M0,
    const float* __restrict__ L0, float* __restrict__ PP, float* __restrict__ W0)
{
  int kc = blockIdx.x;
  int b = blockIdx.z;
  int q0 = blockIdx.y * 32;
  __shared__ u16 P[2][32][136];
  __shared__ u16 KV[2][128][32];

  const int tid = threadIdx.x, lane = tid & 63, wave = tid >> 6;
  const int q4 = lane >> 4, l16 = lane & 15;
  const int wr = (wave >> 1) * 16, wc = (wave & 1) * 64;
  const int srow = wave * 16 + (lane >> 2), scol = (lane & 3) * 8;
  const float alpha = 0.08838834764831845f;

  v8bf qf[2][4];
#pragma unroll
  for (int h = 0; h < 2; h++)
#pragma unroll
    for (int sub = 0; sub < 4; sub++)
      qf[h][sub] = *(const v8bf*)(QHf + ((long)b * 2048 + q0 + wr + l16) * 1024
                                  + h * 128 + sub * 32 + q4 * 8);
  float mv[2][4], il[2][4];
#pragma unroll
  for (int h = 0; h < 2; h++)
#pragma unroll
    for (int i4 = 0; i4 < 4; i4++) {
      long r = (long)(b * 2 + h) * 2048 + q0 + wr + q4 * 4 + i4;
      mv[h][i4] = M0[r];
      il[h][i4] = 1.0f / L0[r];
    }

  const u16* gK = KH + (long)b * 2048 * 256;
  auto stageK = [&](int buf, int h, int kt, int sub) {
    const u16* g = gK + (long)(kt * 128 + srow) * 256 + h * 128 + sub * 32 + scol;
    __builtin_amdgcn_global_load_lds((g_t*)g, (lds_t*)&KV[buf][wave * 16][0], 16, 0, 0);
    __builtin_amdgcn_global_load_lds((g_t*)(g + 64 * 256), (lds_t*)&KV[buf][64 + wave * 16][0], 16, 0, 0);
  };
  auto stageV = [&](int buf, int h, int kt, int sub) {
    const u16* g = VHT + ((long)(b * 2 + h) * 128 + srow) * 2048 + kt * 128 + sub * 32 + scol;
    __builtin_amdgcn_global_load_lds((g_t*)g, (lds_t*)&KV[buf][wave * 16][0], 16, 0, 0);
    __builtin_amdgcn_global_load_lds((g_t*)(g + (long)64 * 2048), (lds_t*)&KV[buf][64 + wave * 16][0], 16, 0, 0);
  };

  v4f acc[2][4];
#pragma unroll
  for (int h = 0; h < 2; h++)
#pragma unroll
    for (int ni = 0; ni < 4; ni++) acc[h][ni] = (v4f){0.f, 0.f, 0.f, 0.f};

  for (int kt = kc * 4; kt < kc * 4 + 4; kt++) {
    float p0[4][4];
#pragma unroll
    for (int h = 0; h < 2; h++) {
      v4f s[4];
#pragma unroll
      for (int ni = 0; ni < 4; ni++) s[ni] = (v4f){0.f, 0.f, 0.f, 0.f};
      stageK(0, h, kt, 0);
      __syncthreads();
      int cur = 0;
#pragma unroll
      for (int sub = 0; sub < 4; sub++) {
        if (sub < 3) stageK(cur ^ 1, h, kt, sub + 1);
        v8bf kf[4];
#pragma unroll
        for (int ni = 0; ni < 4; ni++)
          kf[ni] = *(const v8bf*)&KV[cur][wc + ni * 16 + l16][q4 * 8];
#pragma unroll
        for (int ni = 0; ni < 4; ni++)
          s[ni] = __builtin_amdgcn_mfma_f32_16x16x32_bf16(qf[h][sub], kf[ni], s[ni], 0, 0, 0);
        __syncthreads();
        cur ^= 1;
      }
#pragma unroll
      for (int ni = 0; ni < 4; ni++)
#pragma unroll
        for (int i4 = 0; i4 < 4; i4++) {
          float p = __expf(s[ni][i4] * alpha - mv[h][i4]) * il[h][i4];
          P[h][wr + q4 * 4 + i4][wc + ni * 16 + l16] = f2bf(p);
          if (h == 0) p0[ni][i4] = p;
          else {
            W0[((long)b * 2048 + q0 + wr + q4 * 4 + i4) * 2048
               + kt * 128 + wc + ni * 16 + l16] = 0.5f * (p0[ni][i4] + p);
          }
        }
    }
#pragma unroll
    for (int h = 0; h < 2; h++) {
      stageV(0, h, kt, 0);
      __syncthreads();                 // also makes P writes visible
      int cv = 0;
#pragma unroll
      for (int sub = 0; sub < 4; sub++) {
        if (sub < 3) stageV(cv ^ 1, h, kt, sub + 1);
        v8bf pf = *(const v8bf*)&P[h][wr + l16][sub * 32 + q4 * 8];
        v8bf vf[4];
#pragma unroll
        for (int ni = 0; ni < 4; ni++)
          vf[ni] = *(const v8bf*)&KV[cv][wc + ni * 16 + l16][q4 * 8];
#pragma unroll
        for (int ni = 0; ni < 4; ni++)
          acc[h][ni] = __builtin_amdgcn_mfma_f32_16x16x32_bf16(pf, vf[ni], acc[h][ni], 0, 0, 0);
        __syncthreads();
        cv ^= 1;
      }
    }
  }

  // ---- write fp32 partials (normalized P -> just sum over chunks) ----
  float* pp = PP + ((long)kc * 8192 + (long)b * 2048) * 256;
#pragma unroll
  for (int h = 0; h < 2; h++)
#pragma unroll
    for (int ni = 0; ni < 4; ni++)
#pragma unroll
      for (int i4 = 0; i4 < 4; i4++) {
        int r = q0 + wr + q4 * 4 + i4;
        int c = wc + ni * 16 + l16;
        pp[(long)r * 256 + h * 128 + c] = acc[h][ni][i4];
      }
}

// ---------------- flash attention for scales 1..3 (unchanged) ----------------
__global__ __launch_bounds__(256) void k_flash(
    const u16* __restrict__ QHf, const u16* __restrict__ KH,
    const u16* __restrict__ VHT, u16* __restrict__ AOf)
{
  int z = blockIdx.z;
  int i = (z >> 3) + 1;
  int b = (z >> 1) & 3, h = z & 1;
  int Ls = 2048 >> i;
  int nkt = Ls >> 7;
  long ro = (long)(16384 - (8192 >> (i - 1))) * 256;
  int q0 = blockIdx.y * 64;

  __shared__ u16 QP[64][136];
  __shared__ u16 KV[2][128][32];
  __shared__ float red[2][4][64];

  const int tid = threadIdx.x, lane = tid & 63, wave = tid >> 6;
  const int q4 = lane >> 4, l16 = lane & 15;
  const int wr = (wave >> 1) * 32, wc = (wave & 1) * 64;
  const int srow = wave * 16 + (lane >> 2);
  const int scol = (lane & 3) * 8;

  {
    const u16* gq = QHf + ((long)b * 2048 + q0) * 1024 + i * 256 + h * 128;
    int idx = tid * 4;
#pragma unroll
    for (int j = 0; j < 4; j++) {
      int r = (idx + j) >> 4, ch = (idx + j) & 15;
      *(ulonglong2*)&QP[r][ch * 8] = *(const ulonglong2*)(gq + (long)r * 1024 + ch * 8);
    }
  }
  __syncthreads();
  v8bf qf[2][4];
#pragma unroll
  for (int mi = 0; mi < 2; mi++)
#pragma unroll
    for (int sub = 0; sub < 4; sub++)
      qf[mi][sub] = *(const v8bf*)&QP[wr + mi * 16 + l16][sub * 32 + q4 * 8];
  __syncthreads();

  const u16* gK = KH + ro + (long)b * Ls * 256 + h * 128;
  const u16* gV = VHT + ro + (long)(b * 2 + h) * 128 * Ls;

  auto stageK = [&](int buf, int kt, int sub) {
    const u16* g = gK + (long)(kt * 128 + srow) * 256 + sub * 32 + scol;
    __builtin_amdgcn_global_load_lds((g_t*)g, (lds_t*)&KV[buf][wave * 16][0], 16, 0, 0);
    __builtin_amdgcn_global_load_lds((g_t*)(g + 64 * 256), (lds_t*)&KV[buf][64 + wave * 16][0], 16, 0, 0);
  };
  auto stageV = [&](int buf, int kt, int sub) {
    const u16* g = gV + (long)srow * Ls + kt * 128 + sub * 32 + scol;
    __builtin_amdgcn_global_load_lds((g_t*)g, (lds_t*)&KV[buf][wave * 16][0], 16, 0, 0);
    __builtin_amdgcn_global_load_lds((g_t*)(g + (long)64 * Ls), (lds_t*)&KV[buf][64 + wave * 16][0], 16, 0, 0);
  };

  v4f acc_o[2][4];
  float m_run[2][4], l_run[2][4];
#pragma unroll
  for (int mi = 0; mi < 2; mi++)
#pragma unroll
    for (int ni = 0; ni < 4; ni++) acc_o[mi][ni] = (v4f){0.f, 0.f, 0.f, 0.f};
#pragma unroll
  for (int mi = 0; mi < 2; mi++)
#pragma unroll
    for (int i4 = 0; i4 < 4; i4++) { m_run[mi][i4] = -1e30f; l_run[mi][i4] = 0.f; }

  const float alpha = 0.08838834764831845f;

  for (int kt = 0; kt < nkt; kt++) {
    v4f s[2][4];
#pragma unroll
    for (int mi = 0; mi < 2; mi++)
#pragma unroll
      for (int ni = 0; ni < 4; ni++) s[mi][ni] = (v4f){0.f, 0.f, 0.f, 0.f};
    stageK(0, kt, 0);
    __syncthreads();
    int cur = 0;
#pragma unroll
    for (int sub = 0; sub < 4; sub++) {
      if (sub < 3) stageK(cur ^ 1, kt, sub + 1);
      v8bf kf[4];
#pragma unroll
      for (int ni = 0; ni < 4; ni++)
        kf[ni] = *(const v8bf*)&KV[cur][wc + ni * 16 + l16][q4 * 8];
#pragma unroll
      for (int mi = 0; mi < 2; mi++)
#pragma unroll
        for (int ni = 0; ni < 4; ni++)
          s[mi][ni] = __builtin_amdgcn_mfma_f32_16x16x32_bf16(qf[mi][sub], kf[ni], s[mi][ni], 0, 0, 0);
      __syncthreads();
      cur ^= 1;
    }
    stageV(0, kt, 0);

#pragma unroll
    for (int mi = 0; mi < 2; mi++)
#pragma unroll
      for (int ni = 0; ni < 4; ni++) s[mi][ni] *= alpha;
    float mloc[2][4];
#pragma unroll
    for (int mi = 0; mi < 2; mi++)
#pragma unroll
      for (int i4 = 0; i4 < 4; i4++)
        mloc[mi][i4] = fmaxf(fmaxf(s[mi][0][i4], s[mi][1][i4]),
                             fmaxf(s[mi][2][i4], s[mi][3][i4]));
#pragma unroll
    for (int d = 1; d <= 8; d <<= 1)
#pragma unroll
      for (int mi = 0; mi < 2; mi++)
#pragma unroll
        for (int i4 = 0; i4 < 4; i4++)
          mloc[mi][i4] = fmaxf(mloc[mi][i4], __shfl_xor(mloc[mi][i4], d, 64));
    if (l16 == 0) {
#pragma unroll
      for (int mi = 0; mi < 2; mi++)
#pragma unroll
        for (int i4 = 0; i4 < 4; i4++)
          red[0][wave][wr + mi * 16 + q4 * 4 + i4] = mloc[mi][i4];
    }
    __syncthreads();
    float scl[2][4];
#pragma unroll
    for (int mi = 0; mi < 2; mi++)
#pragma unroll
      for (int i4 = 0; i4 < 4; i4++) {
        int rr = wr + mi * 16 + q4 * 4 + i4;
        float mn = fmaxf(fmaxf(red[0][wave][rr], red[0][wave ^ 1][rr]), m_run[mi][i4]);
        scl[mi][i4] = __expf(m_run[mi][i4] - mn);
        m_run[mi][i4] = mn;
      }
    float lloc[2][4] = {{0.f, 0.f, 0.f, 0.f}, {0.f, 0.f, 0.f, 0.f}};
#pragma unroll
    for (int mi = 0; mi < 2; mi++)
#pragma unroll
      for (int ni = 0; ni < 4; ni++)
#pragma unroll
        for (int i4 = 0; i4 < 4; i4++) {
          float p = __expf(s[mi][ni][i4] - m_run[mi][i4]);
          lloc[mi][i4] += p;
          QP[wr + mi * 16 + q4 * 4 + i4][wc + ni * 16 + l16] = f2bf(p);
        }
#pragma unroll
    for (int d = 1; d <= 8; d <<= 1)
#pragma unroll
      for (int mi = 0; mi < 2; mi++)
#pragma unroll
        for (int i4 = 0; i4 < 4; i4++)
          lloc[mi][i4] += __shfl_xor(lloc[mi][i4], d, 64);
    if (l16 == 0) {
#pragma unroll
      for (int mi = 0; mi < 2; mi++)
#pragma unroll
        for (int i4 = 0; i4 < 4; i4++)
          red[1][wave][wr + mi * 16 + q4 * 4 + i4] = lloc[mi][i4];
    }
#pragma unroll
    for (int mi = 0; mi < 2; mi++)
#pragma unroll
      for (int ni = 0; ni < 4; ni++)
#pragma unroll
        for (int i4 = 0; i4 < 4; i4++) acc_o[mi][ni][i4] *= scl[mi][i4];
    __syncthreads();
#pragma unroll
    for (int mi = 0; mi < 2; mi++)
#pragma unroll
      for (int i4 = 0; i4 < 4; i4++) {
        int rr = wr + mi * 16 + q4 * 4 + i4;
        l_run[mi][i4] = l_run[mi][i4] * scl[mi][i4] + red[1][wave][rr] + red[1][wave ^ 1][rr];
      }

    int cv = 0;
#pragma unroll
    for (int sub = 0; sub < 4; sub++) {
      if (sub < 3) stageV(cv ^ 1, kt, sub + 1);
      v8bf pf[2], vf[4];
#pragma unroll
      for (int mi = 0; mi < 2; mi++)
        pf[mi] = *(const v8bf*)&QP[wr + mi * 16 + l16][sub * 32 + q4 * 8];
#pragma unroll
      for (int ni = 0; ni < 4; ni++)
        vf[ni] = *(const v8bf*)&KV[cv][wc + ni * 16 + l16][q4 * 8];
#pragma unroll
      for (int mi = 0; mi < 2; mi++)
#pragma unroll
        for (int ni = 0; ni < 4; ni++)
          acc_o[mi][ni] = __builtin_amdgcn_mfma_f32_16x16x32_bf16(pf[mi], vf[ni], acc_o[mi][ni], 0, 0, 0);
      __syncthreads();
      cv ^= 1;
    }
  }

#pragma unroll
  for (int mi = 0; mi < 2; mi++)
#pragma unroll
    for (int i4 = 0; i4 < 4; i4++) {
      float inv = 1.0f / l_run[mi][i4];
#pragma unroll
      for (int ni = 0; ni < 4; ni++) {
        int r = q0 + wr + mi * 16 + q4 * 4 + i4;
        int c = wc + ni * 16 + l16;
        AOf[((long)b * 2048 + r) * 1024 + i * 256 + h * 128 + c] =
            f2bf(acc_o[mi][ni][i4] * inv);
      }
    }
}

// ---------------- 128x128-tile batched bf16 MFMA GEMM (double-buffered) ----
template<int WBF>
__global__ __launch_bounds__(256) void k_gemm(
    const u16* __restrict__ A, long ldA, long sA1, long sA2,
    const u16* __restrict__ B, long ldB, long sB1, long sB2,
    void* __restrict__ Cv, long ldC, long sC1, long sC2, long sCk,
    const float* __restrict__ bias, long sBias, float alpha,
    int M, int N, int K, int nz2, int KS)
{
  __shared__ u16 As[2][128][32];
  __shared__ u16 Bs[2][128][32];
  int z = blockIdx.z;
  int ks = z % KS; int zz = z / KS;
  int z1 = zz / nz2, z2 = zz - z1 * nz2;
  A += (long)z1 * sA1 + (long)z2 * sA2 + (long)ks * K;
  B += (long)z1 * sB1 + (long)z2 * sB2 + (long)ks * K;
  long coff = (long)z1 * sC1 + (long)z2 * sC2 + (long)ks * sCk;
  const float* bz = bias ? bias + (long)z2 * sBias : nullptr;
  const int m0 = blockIdx.y * 128, n0 = blockIdx.x * 128;
  const int tid = threadIdx.x;
  const int lane = tid & 63;
  const int wave = tid >> 6;
  const int wr = (wave >> 1) * 64, wc = (wave & 1) * 64;
  const int q4 = lane >> 4, l16 = lane & 15;

  const int srow = wave * 16 + (lane >> 2);
  const int scol = (lane & 3) * 8;
  const u16* gA = A + (long)(m0 + srow) * ldA + scol;
  const u16* gB = B + (long)(n0 + srow) * ldB + scol;

  auto stage = [&](int buf, int kt) {
    __builtin_amdgcn_global_load_lds((g_t*)(gA + kt), (lds_t*)&As[buf][wave * 16][0], 16, 0, 0);
    __builtin_amdgcn_global_load_lds((g_t*)(gA + 64 * ldA + kt), (lds_t*)&As[buf][64 + wave * 16][0], 16, 0, 0);
    __builtin_amdgcn_global_load_lds((g_t*)(gB + kt), (lds_t*)&Bs[buf][wave * 16][0], 16, 0, 0);
    __builtin_amdgcn_global_load_lds((g_t*)(gB + 64 * ldB + kt), (lds_t*)&Bs[buf][64 + wave * 16][0], 16, 0, 0);
  };

  v4f acc[4][4];
#pragma unroll
  for (int i = 0; i < 4; i++)
#pragma unroll
    for (int j = 0; j < 4; j++) acc[i][j] = (v4f){0.f, 0.f, 0.f, 0.f};

  stage(0, 0);
  __syncthreads();
  int cur = 0;
  for (int kt = 0; kt < K; kt += 32) {
    if (kt + 32 < K) stage(cur ^ 1, kt + 32);
    v8bf af[4], bf[4];
#pragma unroll
    for (int i = 0; i < 4; i++) af[i] = *(const v8bf*)&As[cur][wr + i * 16 + l16][q4 * 8];
#pragma unroll
    for (int i = 0; i < 4; i++) bf[i] = *(const v8bf*)&Bs[cur][wc + i * 16 + l16][q4 * 8];
#pragma unroll
    for (int mi = 0; mi < 4; mi++)
#pragma unroll
      for (int ni = 0; ni < 4; ni++)
        acc[mi][ni] = __builtin_amdgcn_mfma_f32_16x16x32_bf16(af[mi], bf[ni], acc[mi][ni], 0, 0, 0);
    __syncthreads();
    cur ^= 1;
  }

#pragma unroll
  for (int mi = 0; mi < 4; mi++) {
    int rb = m0 + wr + mi * 16 + q4 * 4;
#pragma unroll
    for (int ni = 0; ni < 4; ni++) {
      int c = n0 + wc + ni * 16 + l16;
      float bv = bz ? bz[c] : 0.f;
#pragma unroll
      for (int i = 0; i < 4; i++) {
        int r = rb + i;
        float val = acc[mi][ni][i] * alpha + bv;
        if (WBF) ((u16*)Cv)[coff + (long)r * ldC + c] = f2bf(val);
        else     ((float*)Cv)[coff + (long)r * ldC + c] = val;
      }
    }
  }
}

// ---------------- K/V head GEMM, full 128x128 tiles, scale derived from row ----
__global__ __launch_bounds__(256) void k_gemm_kv(
    const u16* __restrict__ Xk, const u16* __restrict__ Xv,
    const u16* __restrict__ WCkv, const float* __restrict__ Bckv,
    u16* __restrict__ KH, u16* __restrict__ VHT)
{
  __shared__ u16 As[2][128][32];
  __shared__ u16 Bs[2][128][32];
  const int isV = blockIdx.z;
  const int m0 = blockIdx.y * 128, n0 = blockIdx.x * 128;
  const int scale = m0 < 8192 ? 0 : (m0 < 12288 ? 1 : (m0 < 14336 ? 2 : 3));
  const int rbase = scale == 0 ? 0 : (scale == 1 ? 8192 : (scale == 2 ? 12288 : 14336));
  const int lsh = 11 - scale;
  const u16* A = isV ? Xv : Xk;
  const u16* B = WCkv + (long)isV * 1048576 + (long)scale * 262144;
  const float* bz = Bckv + isV * 1024 + scale * 256;

  const int tid = threadIdx.x;
  const int lane = tid & 63, wave = tid >> 6;
  const int wr = (wave >> 1) * 64, wc = (wave & 1) * 64;
  const int q4 = lane >> 4, l16 = lane & 15;
  const int srow = wave * 16 + (lane >> 2);
  const int scol = (lane & 3) * 8;
  const u16* gA = A + (long)(m0 + srow) * 1024 + scol;
  const u16* gB = B + (long)(n0 + srow) * 1024 + scol;

  auto stage = [&](int buf, int kt) {
    __builtin_amdgcn_global_load_lds((g_t*)(gA + kt), (lds_t*)&As[buf][wave * 16][0], 16, 0, 0);
    __builtin_amdgcn_global_load_lds((g_t*)(gA + 64 * 1024 + kt), (lds_t*)&As[buf][64 + wave * 16][0], 16, 0, 0);
    __builtin_amdgcn_global_load_lds((g_t*)(gB + kt), (lds_t*)&Bs[buf][wave * 16][0], 16, 0, 0);
    __builtin_amdgcn_global_load_lds((g_t*)(gB + 64 * 1024 + kt), (lds_t*)&Bs[buf][64 + wave * 16][0], 16, 0, 0);
  };

  v4f acc[4][4];
#pragma unroll
  for (int i = 0; i < 4; i++)
#pragma unroll
    for (int j = 0; j < 4; j++) acc[i][j] = (v4f){0.f, 0.f, 0.f, 0.f};

  stage(0, 0);
  __syncthreads();
  int cur = 0;
  for (int kt = 0; kt < 1024; kt += 32) {
    if (kt + 32 < 1024) stage(cur ^ 1, kt + 32);
    v8bf af[4], bf[4];
#pragma unroll
    for (int i = 0; i < 4; i++) af[i] = *(const v8bf*)&As[cur][wr + i * 16 + l16][q4 * 8];
#pragma unroll
    for (int i = 0; i < 4; i++) bf[i] = *(const v8bf*)&Bs[cur][wc + i * 16 + l16][q4 * 8];
#pragma unroll
    for (int mi = 0; mi < 4; mi++)
#pragma unroll
      for (int ni = 0; ni < 4; ni++)
        acc[mi][ni] = __builtin_amdgcn_mfma_f32_16x16x32_bf16(af[mi], bf[ni], acc[mi][ni], 0, 0, 0);
    __syncthreads();
    cur ^= 1;
  }

#pragma unroll
  for (int mi = 0; mi < 4; mi++) {
    int rb = m0 + wr + mi * 16 + q4 * 4;
#pragma unroll
    for (int ni = 0; ni < 4; ni++) {
      int c = n0 + wc + ni * 16 + l16;
      float bv = bz[c];
#pragma unroll
      for (int i = 0; i < 4; i++) {
        int r = rb + i;
        float val = acc[mi][ni][i] + bv;
        if (!isV) {
          KH[(long)r * 256 + c] = f2bf(val);
        } else {
          int rl = r - rbase;
          int b = rl >> lsh, t = rl & ((1 << lsh) - 1);
          int h = c >> 7, n = c & 127;
          VHT[(long)rbase * 256 + (((long)(b * 2 + h) * 128 + n) << lsh) + t] = f2bf(val);
        }
      }
    }
  }
}

extern "C" void kernel_launch(void* const* d_in, const int* in_sizes, int n_in,
                              void* d_out, int out_size, void* d_ws, size_t ws_size,
                              hipStream_t stream) {
  const float* query = (const float*)d_in[0];
  const float* key_  = (const float*)d_in[1];
  const float* value = (const float*)d_in[2];
  const float* wq    = (const float*)d_in[3];
  const float* bq    = (const float*)d_in[4];
  const float* wk    = (const float*)d_in[5];
  const float* bk    = (const float*)d_in[6];
  const float* wv    = (const float*)d_in[7];
  const float* bv    = (const float*)d_in[8];
  const float* in_w  = (const float*)d_in[9];
  const float* in_b  = (const float*)d_in[10];
  const float* out_w = (const float*)d_in[11];
  const float* out_b = (const float*)d_in[12];
  const float* fus_w = (const float*)d_in[13];
  const float* fus_b = (const float*)d_in[14];
  (void)in_sizes; (void)n_in; (void)out_size; (void)ws_size;

  float* outF  = (float*)d_out;
  float* outW0 = outF + (long)4 * 2048 * 1024;

  // ---- workspace layout ----
  char* base = (char*)d_ws;
  size_t off = 0;
  auto alloc = [&](size_t bytes) -> void* {
    void* p = base + off;
    off = (off + bytes + 255) & ~(size_t)255;
    return p;
  };
  const long NX = (long)8192 * 1024;
  u16* Winb = (u16*)alloc((size_t)4 * 768 * 256 * 2);     // bf16 in_w
  u16* Wfb  = (u16*)alloc((size_t)1024 * 1024 * 2);       // bf16 fus_w
  u16* WoT  = (u16*)alloc((size_t)4 * 256 * 256 * 2);     // bf16 out_w^T (per scale)
  u16* WT   = (u16*)alloc((size_t)3 * 1024 * 1024 * 2);   // bf16 wq^T|wk^T|wv^T
  u16* WC   = (u16*)alloc((size_t)3 * 1024 * 1024 * 2);   // combined WQc|WKc|WVc
  u16* WFc  = (u16*)alloc((size_t)1024 * 1024 * 2);       // combined final weight
  float* Bc  = (float*)alloc((size_t)3 * 1024 * 4);       // combined bQc|bKc|bVc
  float* fbc = (float*)alloc((size_t)1024 * 4);           // combined final bias
  u16* Xq    = (u16*)alloc((size_t)NX * 2);
  u16* XkAll = (u16*)alloc((size_t)15360 * 1024 * 2);
  u16* XvAll = (u16*)alloc((size_t)15360 * 1024 * 2);
  u16* QHf = (u16*)alloc((size_t)8192 * 1024 * 2);        // heads of Q, 1024-wide
  u16* KH  = (u16*)alloc((size_t)15360 * 256 * 2);
  u16* VHT = (u16*)alloc((size_t)15360 * 256 * 2);
  float* M0 = (float*)alloc((size_t)8 * 2048 * 4);        // scale-0 row max
  float* L0 = (float*)alloc((size_t)8 * 2048 * 4);        // scale-0 row denom
  float* Mp = (float*)alloc((size_t)4 * 8 * 2048 * 4);    // partial m
  float* Lp = (float*)alloc((size_t)4 * 8 * 2048 * 4);    // partial l
  float* PP = (float*)alloc((size_t)4 * 8192 * 256 * 4);  // scale-0 split-K partials
  u16* AOf = (u16*)alloc((size_t)8192 * 1024 * 2);        // attended concat, 1024-wide

  const long AOsz = (long)8192 * 256;

  // ---- converts / transposes / pooling ----
  k_cvt<<<1024, 256, 0, stream>>>(query, Xq, NX);
  k_cvtpool<<<1024, 256, 0, stream>>>(key_,  XkAll);
  k_cvtpool<<<1024, 256, 0, stream>>>(value, XvAll);
  k_cvt<<<192, 256, 0, stream>>>(in_w, Winb, 4 * 768 * 256);
  k_cvt<<<256, 256, 0, stream>>>(fus_w, Wfb, 1024 * 1024);
  k_tc<<<dim3(32, 32, 1), 256, 0, stream>>>(wq, WT, 1024, 1024);
  k_tc<<<dim3(32, 32, 1), 256, 0, stream>>>(wk, WT + (long)1024 * 1024, 1024, 1024);
  k_tc<<<dim3(32, 32, 1), 256, 0, stream>>>(wv, WT + (long)2 * 1024 * 1024, 1024, 1024);
  k_tc<<<dim3(8, 8, 4), 256, 0, stream>>>(out_w, WoT, 256, 256);
  k_bcomb_qkv<<<768, 256, 0, stream>>>(in_w, in_b, bq, bk, bv, Bc);
  k_bcomb_f<<<256, 256, 0, stream>>>(fus_w, fus_b, out_b, fbc);

  // ---- weight combines ----
  k_gemm<1><<<dim3(8, 2, 12), 256, 0, stream>>>(
      Winb, 256, 65536, 196608,
      WT, 1024, 1048576, 256,
      WC, 1024, 1048576, 262144, 0,
      nullptr, 0, 1.f, 256, 1024, 256, 4, 1);
  k_gemm<1><<<dim3(2, 8, 4), 256, 0, stream>>>(
      Wfb, 1024, 0, 256,
      WoT, 256, 0, 65536,
      WFc, 1024, 0, 256, 0,
      nullptr, 0, 1.f, 1024, 256, 256, 4, 1);

  // ---- head projections ----
  k_gemm<1><<<dim3(8, 64, 1), 256, 0, stream>>>(
      Xq, 1024, 0, 0, WC, 1024, 0, 0,
      QHf, 1024, 0, 0, 0, Bc, 0, 1.f, 8192, 1024, 1024, 1, 1);
  k_gemm_kv<<<dim3(2, 120, 2), 256, 0, stream>>>(
      XkAll, XvAll, WC + (long)1024 * 1024, Bc + 1024, KH, VHT);

  // ---- scale 0: split-K two-pass fused ----
  k_ml0<<<dim3(4, 32, 8), 256, 0, stream>>>(QHf, KH, Mp, Lp);
  k_mlcomb<<<64, 256, 0, stream>>>(Mp, Lp, M0, L0);
  k_pv0<<<dim3(4, 64, 4), 256, 0, stream>>>(QHf, KH, VHT, M0, L0, PP, outW0);
  k_ksum<4><<<2048, 256, 0, stream>>>(PP, AOf, AOsz, 0);

  // ---- scales 1..3: fused flash attention ----
  k_flash<<<dim3(1, 32, 24), 256, 0, stream>>>(QHf, KH, VHT, AOf);

  // ---- final (fused out-proj + fusion): fused = AOf @ WFc^T + fbc ----
  k_gemm<0><<<dim3(8, 64, 1), 256, 0, stream>>>(
      AOf, 1024, 0, 0, WFc, 1024, 0, 0,
      outF, 1024, 0, 0, 0, fbc, 0, 1.f, 8192, 1024, 1024, 1, 1);
}